// Round 3
// baseline (1457.996 us; speedup 1.0000x reference)
//
#include <hip/hip_runtime.h>
#include <hip/hip_bf16.h>

// Problem dims (fixed)
#define BB 256   // batch
#define SS 128   // seq len
#define EE 512   // embed dim
#define HH 1024  // hidden
#define VV 128   // vocab
#define CC 18    // classes

typedef _Float16 f16x8 __attribute__((ext_vector_type(8)));
typedef _Float16 f16x4 __attribute__((ext_vector_type(4)));
typedef float    f32x4 __attribute__((ext_vector_type(4)));

// ws layout (bytes)
//  0x000000: _Float16 hbuf[2][2][256][1024]   (2 MB)  [buf][hi/lo][b][k]; buf0 zeroed
//  0x200000: int flags[16][128]               (8 KB)  per-(group,step) arrival counters
//  0x210000: float emb_proj[128][1024]        (512 KB) = emb@W_ih^T + b_ih + b_hh
//  0x290000: float last[256][1024]            (1 MB)  gathered final hidden
//  0x390000: float z[256][1024]               (1 MB)  relu(last@W1^T + b1)
#define HBUF_OFF  0x000000
#define FLAGS_OFF 0x200000
#define EP_OFF    0x210000
#define LAST_OFF  0x290000
#define Z_OFF     0x390000

__device__ inline f16x8 cvt8(f32x4 a, f32x4 b) {
  f16x8 r;
  r[0] = (_Float16)a.x; r[1] = (_Float16)a.y; r[2] = (_Float16)a.z; r[3] = (_Float16)a.w;
  r[4] = (_Float16)b.x; r[5] = (_Float16)b.y; r[6] = (_Float16)b.z; r[7] = (_Float16)b.w;
  return r;
}

// ---------------- K1: emb_proj[v][h] = sum_e emb[v][e]*W_ih[h][e] + b_ih[h] + b_hh[h]
// 128 blocks: 8 v-tiles(16) x 16 h-tiles(64). Waves k-split K=512 (128 each), LDS reduce.
__global__ __launch_bounds__(256) void k_embproj(const float* __restrict__ emb,
                                                 const float* __restrict__ W_ih,
                                                 const float* __restrict__ b_ih,
                                                 const float* __restrict__ b_hh,
                                                 float* __restrict__ ep) {
  __shared__ float red[4][16][66];
  const int bid = blockIdx.x;
  const int v0 = (bid & 7) * 16;
  const int h0 = (bid >> 3) * 64;
  const int tid = threadIdx.x;
  const int w = tid >> 6, lane = tid & 63, lr = lane & 15, lk = lane >> 4;

  f32x4 acc[4] = {};
  const int vrow = v0 + lr;
#pragma unroll
  for (int ki = 0; ki < 4; ++ki) {
    const int k = w * 128 + ki * 32 + lk * 8;
    const f32x4* pa = (const f32x4*)(emb + vrow * EE + k);
    f16x8 af = cvt8(pa[0], pa[1]);
#pragma unroll
    for (int nt = 0; nt < 4; ++nt) {
      const int hcol = h0 + nt * 16 + lr;
      const f32x4* pb = (const f32x4*)(W_ih + hcol * EE + k);
      f16x8 bf = cvt8(pb[0], pb[1]);
      acc[nt] = __builtin_amdgcn_mfma_f32_16x16x32_f16(af, bf, acc[nt], 0, 0, 0);
    }
  }
#pragma unroll
  for (int nt = 0; nt < 4; ++nt)
#pragma unroll
    for (int j = 0; j < 4; ++j)
      red[w][lk * 4 + j][nt * 16 + lr] = acc[nt][j];
  __syncthreads();

  const int r = tid >> 4, cg = tid & 15, cc0 = cg * 4;
  const int vvr = v0 + r;
#pragma unroll
  for (int i = 0; i < 4; ++i) {
    const int hcol = h0 + cc0 + i;
    float s = red[0][r][cc0 + i] + red[1][r][cc0 + i] +
              red[2][r][cc0 + i] + red[3][r][cc0 + i];
    ep[vvr * HH + hcol] = s + b_ih[hcol] + b_hh[hcol];
  }
}

// ---------------- K2: persistent RNN scan.
// 256 blocks = 16 groups (16 batch rows) x 16 col-blocks (64 cols). Groups fully
// independent -> group-local 16-block barrier per step. W_hh frags register-resident
// (f16, 128 VGPR/lane). h state: f16 hi + f16 lo*4096 planes, double-buffered.
// Group members all have the same bid%8 -> same XCD under round-robin dispatch,
// so barrier + h traffic stays within one L2 (perf hint only, not correctness).
__global__ __launch_bounds__(256) void k_rnn(const float* __restrict__ W_hh,
                                             const int* __restrict__ x_in,
                                             const int* __restrict__ x_len,
                                             const float* __restrict__ ep,
                                             _Float16* __restrict__ hbuf,
                                             int* __restrict__ flags,
                                             float* __restrict__ lastb) {
  __shared__ float red[4][16][66];
  __shared__ int xin[16][128];
  __shared__ int len1[16];

  const int bid = blockIdx.x;
  const int g = bid & 15;        // group id
  const int c = bid >> 4;        // col-block
  const int row0 = g * 16, col0 = c * 64;
  const int tid = threadIdx.x;
  const int w = tid >> 6, lane = tid & 63, lr = lane & 15, lk = lane >> 4;

  for (int i = tid; i < 16 * SS; i += 256) {
    const int r = i >> 7, s = i & 127;
    xin[r][s] = x_in[(row0 + r) * SS + s];
  }
  if (tid < 16) len1[tid] = x_len[row0 + tid] - 1;

  // Register-resident W_hh fragments: wave w owns k-quarter [256w, 256w+256)
  f16x8 wreg[4][8];
#pragma unroll
  for (int nt = 0; nt < 4; ++nt) {
    const int col = col0 + nt * 16 + lr;
#pragma unroll
    for (int ki = 0; ki < 8; ++ki) {
      const int k = w * 256 + ki * 32 + lk * 8;
      const f32x4* pw = (const f32x4*)(W_hh + col * HH + k);
      wreg[nt][ki] = cvt8(pw[0], pw[1]);
    }
  }
  __syncthreads();

  const int arow = row0 + lr;
  const int r = tid >> 4, cc0 = (tid & 15) * 4;
  for (int t = 0; t < SS; ++t) {
    const int bufR = t & 1;
    const _Float16* hr_hi = hbuf + ((size_t)(bufR * 2 + 0) * BB + arow) * HH;
    const _Float16* hr_lo = hbuf + ((size_t)(bufR * 2 + 1) * BB + arow) * HH;

    f32x4 acch[4] = {};
    f32x4 accl[4] = {};
#pragma unroll
    for (int ki = 0; ki < 8; ++ki) {
      const int k = w * 256 + ki * 32 + lk * 8;
      f16x8 ahi = *(const f16x8*)(hr_hi + k);
      f16x8 alo = *(const f16x8*)(hr_lo + k);
#pragma unroll
      for (int nt = 0; nt < 4; ++nt) {
        acch[nt] = __builtin_amdgcn_mfma_f32_16x16x32_f16(ahi, wreg[nt][ki], acch[nt], 0, 0, 0);
        accl[nt] = __builtin_amdgcn_mfma_f32_16x16x32_f16(alo, wreg[nt][ki], accl[nt], 0, 0, 0);
      }
    }
#pragma unroll
    for (int nt = 0; nt < 4; ++nt)
#pragma unroll
      for (int j = 0; j < 4; ++j)
        red[w][lk * 4 + j][nt * 16 + lr] = acch[nt][j] + accl[nt][j] * (1.0f / 4096.0f);

    // issue the gather for this step's input projection BEFORE the barrier,
    // so its latency hides under the LDS reduce
    const int vv = xin[r][t];
    const f32x4 pre4 = *(const f32x4*)(ep + vv * HH + col0 + cc0);
    __syncthreads();

    float sv[4];
#pragma unroll
    for (int i = 0; i < 4; ++i)
      sv[i] = red[0][r][cc0 + i] + red[1][r][cc0 + i] +
              red[2][r][cc0 + i] + red[3][r][cc0 + i];

    float th[4];
#pragma unroll
    for (int i = 0; i < 4; ++i) {
      const float x = sv[i] + ((i == 0) ? pre4.x : (i == 1) ? pre4.y : (i == 2) ? pre4.z : pre4.w);
      const float e = __expf(-2.0f * fabsf(x));
      th[i] = copysignf((1.0f - e) / (1.0f + e), x);
    }

    const int bufW = bufR ^ 1;
    const int grow = row0 + r;
    f16x4 h4, l4;
#pragma unroll
    for (int i = 0; i < 4; ++i) {
      const _Float16 hh = (_Float16)th[i];
      h4[i] = hh;
      l4[i] = (_Float16)((th[i] - (float)hh) * 4096.0f);
    }
    *(f16x4*)(hbuf + ((size_t)(bufW * 2 + 0) * BB + grow) * HH + col0 + cc0) = h4;
    *(f16x4*)(hbuf + ((size_t)(bufW * 2 + 1) * BB + grow) * HH + col0 + cc0) = l4;

    if (len1[r] == t) {
      f32x4 o; o.x = th[0]; o.y = th[1]; o.z = th[2]; o.w = th[3];
      *(f32x4*)(lastb + (size_t)grow * HH + col0 + cc0) = o;
    }

    if (t < SS - 1) {
      // __syncthreads drains vmcnt(0) -> all this block's h stores are visible
      __syncthreads();
      if (tid == 0) {
        __hip_atomic_fetch_add(&flags[g * SS + t], 1, __ATOMIC_RELEASE,
                               __HIP_MEMORY_SCOPE_AGENT);
        // acquire on the load that observes the 16th arrival synchronizes-with
        // all 16 release-adds; no separate fence intrinsic needed
        while (__hip_atomic_load(&flags[g * SS + t], __ATOMIC_ACQUIRE,
                                 __HIP_MEMORY_SCOPE_AGENT) < 16) {
          __builtin_amdgcn_s_sleep(2);   // backoff: keep the flag line quiet
        }
      }
      __syncthreads();
    }
  }
}

// ---------------- K3: z = relu(last @ W1^T + b1). Same MFMA tile as RNN step,
// A (last) split hi/lo, W1 streamed f16. 256 blocks: 16x16 tiles of 16x64.
__global__ __launch_bounds__(256) void k_mlp1(const float* __restrict__ lastb,
                                              const float* __restrict__ W1,
                                              const float* __restrict__ b1,
                                              float* __restrict__ z) {
  __shared__ float red[4][16][66];
  const int bid = blockIdx.x;
  const int row0 = (bid & 15) * 16, col0 = (bid >> 4) * 64;
  const int tid = threadIdx.x;
  const int w = tid >> 6, lane = tid & 63, lr = lane & 15, lk = lane >> 4;
  const int arow = row0 + lr;

  f32x4 acch[4] = {};
  f32x4 accl[4] = {};
#pragma unroll
  for (int ki = 0; ki < 8; ++ki) {
    const int k = w * 256 + ki * 32 + lk * 8;
    const f32x4* pa = (const f32x4*)(lastb + (size_t)arow * HH + k);
    f32x4 a0 = pa[0], a1 = pa[1];
    f16x8 ahi, alo;
#pragma unroll
    for (int i = 0; i < 4; ++i) {
      float v0 = (i == 0) ? a0.x : (i == 1) ? a0.y : (i == 2) ? a0.z : a0.w;
      float v1 = (i == 0) ? a1.x : (i == 1) ? a1.y : (i == 2) ? a1.z : a1.w;
      _Float16 h0 = (_Float16)v0, h1 = (_Float16)v1;
      ahi[i] = h0; ahi[i + 4] = h1;
      alo[i] = (_Float16)((v0 - (float)h0) * 4096.0f);
      alo[i + 4] = (_Float16)((v1 - (float)h1) * 4096.0f);
    }
#pragma unroll
    for (int nt = 0; nt < 4; ++nt) {
      const int colw = col0 + nt * 16 + lr;
      const f32x4* pb = (const f32x4*)(W1 + (size_t)colw * HH + k);
      f16x8 bf = cvt8(pb[0], pb[1]);
      acch[nt] = __builtin_amdgcn_mfma_f32_16x16x32_f16(ahi, bf, acch[nt], 0, 0, 0);
      accl[nt] = __builtin_amdgcn_mfma_f32_16x16x32_f16(alo, bf, accl[nt], 0, 0, 0);
    }
  }
#pragma unroll
  for (int nt = 0; nt < 4; ++nt)
#pragma unroll
    for (int j = 0; j < 4; ++j)
      red[w][lk * 4 + j][nt * 16 + lr] = acch[nt][j] + accl[nt][j] * (1.0f / 4096.0f);
  __syncthreads();

  const int r = tid >> 4, cc0 = (tid & 15) * 4;
  const int grow = row0 + r;
#pragma unroll
  for (int i = 0; i < 4; ++i) {
    const int col = col0 + cc0 + i;
    float s = red[0][r][cc0 + i] + red[1][r][cc0 + i] +
              red[2][r][cc0 + i] + red[3][r][cc0 + i] + b1[col];
    z[(size_t)grow * HH + col] = fmaxf(s, 0.0f);
  }
}

// ---------------- K4: y = z @ W2^T + b2. One block per batch row, fp32 wave reduce.
__global__ __launch_bounds__(256) void k_mlp2(const float* __restrict__ z,
                                              const float* __restrict__ W2,
                                              const float* __restrict__ b2,
                                              float* __restrict__ out) {
  __shared__ float redy[4][CC];
  const int b = blockIdx.x;
  const int tid = threadIdx.x;
  const int w = tid >> 6, lane = tid & 63;
  const int k = w * 256 + lane * 4;

  const f32x4 z4 = *(const f32x4*)(z + (size_t)b * HH + k);
  float part[CC];
#pragma unroll
  for (int c = 0; c < CC; ++c) {
    const f32x4 w4 = *(const f32x4*)(W2 + (size_t)c * HH + k);
    part[c] = z4.x * w4.x + z4.y * w4.y + z4.z * w4.z + z4.w * w4.w;
  }
#pragma unroll
  for (int c = 0; c < CC; ++c) {
    float v = part[c];
    for (int off = 32; off; off >>= 1) v += __shfl_down(v, off, 64);
    if (lane == 0) redy[w][c] = v;
  }
  __syncthreads();
  if (tid < CC)
    out[b * CC + tid] = redy[0][tid] + redy[1][tid] + redy[2][tid] + redy[3][tid] + b2[tid];
}

extern "C" void kernel_launch(void* const* d_in, const int* in_sizes, int n_in,
                              void* d_out, int out_size, void* d_ws, size_t ws_size,
                              hipStream_t stream) {
  const int*   x_in  = (const int*)d_in[0];
  const int*   x_len = (const int*)d_in[1];
  const float* emb   = (const float*)d_in[2];
  const float* W_ih  = (const float*)d_in[3];
  const float* b_ih  = (const float*)d_in[4];
  const float* W_hh  = (const float*)d_in[5];
  const float* b_hh  = (const float*)d_in[6];
  const float* W1    = (const float*)d_in[7];
  const float* b1    = (const float*)d_in[8];
  const float* W2    = (const float*)d_in[9];
  const float* b2    = (const float*)d_in[10];

  char* ws = (char*)d_ws;
  _Float16* hbuf = (_Float16*)(ws + HBUF_OFF);
  int* flags     = (int*)(ws + FLAGS_OFF);
  float* ep      = (float*)(ws + EP_OFF);
  float* lastb   = (float*)(ws + LAST_OFF);
  float* z       = (float*)(ws + Z_OFF);

  // h0 = 0 (both planes of buf0) and step-arrival flags = 0
  (void)hipMemsetAsync(hbuf, 0, 0x100000, stream);
  (void)hipMemsetAsync(flags, 0, 16 * SS * 4, stream);

  hipLaunchKernelGGL(k_embproj, dim3(128), dim3(256), 0, stream, emb, W_ih, b_ih, b_hh, ep);
  hipLaunchKernelGGL(k_rnn,    dim3(256), dim3(256), 0, stream, W_hh, x_in, x_len, ep, hbuf, flags, lastb);
  hipLaunchKernelGGL(k_mlp1,   dim3(256), dim3(256), 0, stream, lastb, W1, b1, z);
  hipLaunchKernelGGL(k_mlp2,   dim3(256), dim3(256), 0, stream, z, W2, b2, (float*)d_out);
}

// Round 4
// 768.055 us; speedup vs baseline: 1.8983x; 1.8983x over previous
//
#include <hip/hip_runtime.h>
#include <hip/hip_bf16.h>

// Problem dims (fixed)
#define BB 256   // batch
#define SS 128   // seq len
#define EE 512   // embed dim
#define HH 1024  // hidden
#define VV 128   // vocab
#define CC 18    // classes

typedef _Float16 f16x8 __attribute__((ext_vector_type(8)));
typedef _Float16 f16x4 __attribute__((ext_vector_type(4)));
typedef float    f32x4 __attribute__((ext_vector_type(4)));

// ws layout (bytes)
//  0x000000: _Float16 hbuf[2][2][256][1024]   (2 MB)  [buf][hi/lo][b][k]; buf0 zeroed
//  0x200000: int flags[16][128]               (8 KB)  per-(group,step) arrival counters
//  0x210000: float emb_proj[128][1024]        (512 KB) = emb@W_ih^T + b_ih + b_hh
//  0x290000: float last[256][1024]            (1 MB)  gathered final hidden
//  0x390000: float z[256][1024]               (1 MB)  relu(last@W1^T + b1)
#define HBUF_OFF  0x000000
#define FLAGS_OFF 0x200000
#define EP_OFF    0x210000
#define LAST_OFF  0x290000
#define Z_OFF     0x390000

__device__ inline f16x8 cvt8(f32x4 a, f32x4 b) {
  f16x8 r;
  r[0] = (_Float16)a.x; r[1] = (_Float16)a.y; r[2] = (_Float16)a.z; r[3] = (_Float16)a.w;
  r[4] = (_Float16)b.x; r[5] = (_Float16)b.y; r[6] = (_Float16)b.z; r[7] = (_Float16)b.w;
  return r;
}

// Coherence-point (MALL) access helpers: relaxed agent-scope atomics compile to
// global_load/store with sc1 => bypass the non-coherent per-XCD L2. This is the
// whole cross-block h-exchange protocol: no acquire/release fences are needed
// because producer stores and the flag add complete in order at the same
// coherence point (vmcnt-drained by __syncthreads before the add), and consumer
// loads read that point directly.
__device__ inline f16x8 ld_cp16(const _Float16* p) {
  const unsigned long long* q = (const unsigned long long*)p;
  union { unsigned long long u[2]; f16x8 v; } r;
  r.u[0] = __hip_atomic_load(q + 0, __ATOMIC_RELAXED, __HIP_MEMORY_SCOPE_AGENT);
  r.u[1] = __hip_atomic_load(q + 1, __ATOMIC_RELAXED, __HIP_MEMORY_SCOPE_AGENT);
  return r.v;
}
__device__ inline void st_cp8(_Float16* p, f16x4 v) {
  union { f16x4 v; unsigned long long u; } c; c.v = v;
  __hip_atomic_store((unsigned long long*)p, c.u, __ATOMIC_RELAXED,
                     __HIP_MEMORY_SCOPE_AGENT);
}

// ---------------- K1: emb_proj[v][h] = sum_e emb[v][e]*W_ih[h][e] + b_ih[h] + b_hh[h]
// 128 blocks: 8 v-tiles(16) x 16 h-tiles(64). Waves k-split K=512 (128 each), LDS reduce.
__global__ __launch_bounds__(256) void k_embproj(const float* __restrict__ emb,
                                                 const float* __restrict__ W_ih,
                                                 const float* __restrict__ b_ih,
                                                 const float* __restrict__ b_hh,
                                                 float* __restrict__ ep) {
  __shared__ float red[4][16][66];
  const int bid = blockIdx.x;
  const int v0 = (bid & 7) * 16;
  const int h0 = (bid >> 3) * 64;
  const int tid = threadIdx.x;
  const int w = tid >> 6, lane = tid & 63, lr = lane & 15, lk = lane >> 4;

  f32x4 acc[4] = {};
  const int vrow = v0 + lr;
#pragma unroll
  for (int ki = 0; ki < 4; ++ki) {
    const int k = w * 128 + ki * 32 + lk * 8;
    const f32x4* pa = (const f32x4*)(emb + vrow * EE + k);
    f16x8 af = cvt8(pa[0], pa[1]);
#pragma unroll
    for (int nt = 0; nt < 4; ++nt) {
      const int hcol = h0 + nt * 16 + lr;
      const f32x4* pb = (const f32x4*)(W_ih + hcol * EE + k);
      f16x8 bf = cvt8(pb[0], pb[1]);
      acc[nt] = __builtin_amdgcn_mfma_f32_16x16x32_f16(af, bf, acc[nt], 0, 0, 0);
    }
  }
#pragma unroll
  for (int nt = 0; nt < 4; ++nt)
#pragma unroll
    for (int j = 0; j < 4; ++j)
      red[w][lk * 4 + j][nt * 16 + lr] = acc[nt][j];
  __syncthreads();

  const int r = tid >> 4, cg = tid & 15, cc0 = cg * 4;
  const int vvr = v0 + r;
#pragma unroll
  for (int i = 0; i < 4; ++i) {
    const int hcol = h0 + cc0 + i;
    float s = red[0][r][cc0 + i] + red[1][r][cc0 + i] +
              red[2][r][cc0 + i] + red[3][r][cc0 + i];
    ep[vvr * HH + hcol] = s + b_ih[hcol] + b_hh[hcol];
  }
}

// ---------------- K2: persistent RNN scan.
// 256 blocks = 16 groups (16 batch rows) x 16 col-blocks (64 cols). Groups fully
// independent -> group-local 16-block counting barrier per step, all data exchange
// via the MALL (sc1). W_hh frags register-resident (f16, 128 VGPR/lane). h state:
// f16 hi + f16 lo*4096 planes, double-buffered.
__global__ __launch_bounds__(256) void k_rnn(const float* __restrict__ W_hh,
                                             const int* __restrict__ x_in,
                                             const int* __restrict__ x_len,
                                             const float* __restrict__ ep,
                                             _Float16* __restrict__ hbuf,
                                             int* __restrict__ flags,
                                             float* __restrict__ lastb) {
  __shared__ float red[4][16][66];
  __shared__ int xin[16][128];
  __shared__ int len1[16];

  const int bid = blockIdx.x;
  const int g = bid & 15;        // group id
  const int c = bid >> 4;        // col-block
  const int row0 = g * 16, col0 = c * 64;
  const int tid = threadIdx.x;
  const int w = tid >> 6, lane = tid & 63, lr = lane & 15, lk = lane >> 4;

  for (int i = tid; i < 16 * SS; i += 256) {
    const int r = i >> 7, s = i & 127;
    xin[r][s] = x_in[(row0 + r) * SS + s];
  }
  if (tid < 16) len1[tid] = x_len[row0 + tid] - 1;

  // Register-resident W_hh fragments: wave w owns k-quarter [256w, 256w+256)
  f16x8 wreg[4][8];
#pragma unroll
  for (int nt = 0; nt < 4; ++nt) {
    const int col = col0 + nt * 16 + lr;
#pragma unroll
    for (int ki = 0; ki < 8; ++ki) {
      const int k = w * 256 + ki * 32 + lk * 8;
      const f32x4* pw = (const f32x4*)(W_hh + col * HH + k);
      wreg[nt][ki] = cvt8(pw[0], pw[1]);
    }
  }
  __syncthreads();

  // All threads compute the group's max step (identical across the 16 blocks of
  // the group -> identical trip counts -> consistent barrier usage).
  int gmax = 0;
#pragma unroll
  for (int r16 = 0; r16 < 16; ++r16) gmax = max(gmax, len1[r16]);

  const int arow = row0 + lr;
  const int r = tid >> 4, cc0 = (tid & 15) * 4;
  for (int t = 0; t <= gmax; ++t) {
    const int bufR = t & 1;
    const _Float16* hr_hi = hbuf + ((size_t)(bufR * 2 + 0) * BB + arow) * HH;
    const _Float16* hr_lo = hbuf + ((size_t)(bufR * 2 + 1) * BB + arow) * HH;

    f32x4 acch[4] = {};
    f32x4 accl[4] = {};
#pragma unroll
    for (int ki = 0; ki < 8; ++ki) {
      const int k = w * 256 + ki * 32 + lk * 8;
      f16x8 ahi = ld_cp16(hr_hi + k);
      f16x8 alo = ld_cp16(hr_lo + k);
#pragma unroll
      for (int nt = 0; nt < 4; ++nt) {
        acch[nt] = __builtin_amdgcn_mfma_f32_16x16x32_f16(ahi, wreg[nt][ki], acch[nt], 0, 0, 0);
        accl[nt] = __builtin_amdgcn_mfma_f32_16x16x32_f16(alo, wreg[nt][ki], accl[nt], 0, 0, 0);
      }
    }
#pragma unroll
    for (int nt = 0; nt < 4; ++nt)
#pragma unroll
      for (int j = 0; j < 4; ++j)
        red[w][lk * 4 + j][nt * 16 + lr] = acch[nt][j] + accl[nt][j] * (1.0f / 4096.0f);

    // issue the gather for this step's input projection BEFORE the barrier,
    // so its latency hides under the LDS reduce
    const int vv = xin[r][t];
    const f32x4 pre4 = *(const f32x4*)(ep + vv * HH + col0 + cc0);
    __syncthreads();

    float sv[4];
#pragma unroll
    for (int i = 0; i < 4; ++i)
      sv[i] = red[0][r][cc0 + i] + red[1][r][cc0 + i] +
              red[2][r][cc0 + i] + red[3][r][cc0 + i];

    float th[4];
#pragma unroll
    for (int i = 0; i < 4; ++i) {
      const float x = sv[i] + ((i == 0) ? pre4.x : (i == 1) ? pre4.y : (i == 2) ? pre4.z : pre4.w);
      const float e = __expf(-2.0f * fabsf(x));
      th[i] = copysignf((1.0f - e) / (1.0f + e), x);
    }

    const int bufW = bufR ^ 1;
    const int grow = row0 + r;
    f16x4 h4, l4;
#pragma unroll
    for (int i = 0; i < 4; ++i) {
      const _Float16 hh = (_Float16)th[i];
      h4[i] = hh;
      l4[i] = (_Float16)((th[i] - (float)hh) * 4096.0f);
    }

    if (len1[r] == t) {
      f32x4 o; o.x = th[0]; o.y = th[1]; o.z = th[2]; o.w = th[3];
      *(f32x4*)(lastb + (size_t)grow * HH + col0 + cc0) = o;
    }

    if (t < gmax) {
      // write-through h to the coherence point
      st_cp8(hbuf + ((size_t)(bufW * 2 + 0) * BB + grow) * HH + col0 + cc0, h4);
      st_cp8(hbuf + ((size_t)(bufW * 2 + 1) * BB + grow) * HH + col0 + cc0, l4);

      // __syncthreads drains vmcnt(0): every thread's sc1 stores have completed
      // at the coherence point before any thread proceeds.
      __syncthreads();
      if (tid == 0) {
        __hip_atomic_fetch_add(&flags[g * SS + t], 1, __ATOMIC_RELAXED,
                               __HIP_MEMORY_SCOPE_AGENT);
        while (__hip_atomic_load(&flags[g * SS + t], __ATOMIC_RELAXED,
                                 __HIP_MEMORY_SCOPE_AGENT) < 16) {
          __builtin_amdgcn_s_sleep(1);
        }
      }
      __syncthreads();
      asm volatile("" ::: "memory");  // no hoisting of next-step loads above the barrier
    }
  }
}

// ---------------- K3: z = relu(last @ W1^T + b1). Same MFMA tile as RNN step,
// A (last) split hi/lo, W1 streamed f16. 256 blocks: 16x16 tiles of 16x64.
__global__ __launch_bounds__(256) void k_mlp1(const float* __restrict__ lastb,
                                              const float* __restrict__ W1,
                                              const float* __restrict__ b1,
                                              float* __restrict__ z) {
  __shared__ float red[4][16][66];
  const int bid = blockIdx.x;
  const int row0 = (bid & 15) * 16, col0 = (bid >> 4) * 64;
  const int tid = threadIdx.x;
  const int w = tid >> 6, lane = tid & 63, lr = lane & 15, lk = lane >> 4;
  const int arow = row0 + lr;

  f32x4 acch[4] = {};
  f32x4 accl[4] = {};
#pragma unroll
  for (int ki = 0; ki < 8; ++ki) {
    const int k = w * 256 + ki * 32 + lk * 8;
    const f32x4* pa = (const f32x4*)(lastb + (size_t)arow * HH + k);
    f32x4 a0 = pa[0], a1 = pa[1];
    f16x8 ahi, alo;
#pragma unroll
    for (int i = 0; i < 4; ++i) {
      float v0 = (i == 0) ? a0.x : (i == 1) ? a0.y : (i == 2) ? a0.z : a0.w;
      float v1 = (i == 0) ? a1.x : (i == 1) ? a1.y : (i == 2) ? a1.z : a1.w;
      _Float16 h0 = (_Float16)v0, h1 = (_Float16)v1;
      ahi[i] = h0; ahi[i + 4] = h1;
      alo[i] = (_Float16)((v0 - (float)h0) * 4096.0f);
      alo[i + 4] = (_Float16)((v1 - (float)h1) * 4096.0f);
    }
#pragma unroll
    for (int nt = 0; nt < 4; ++nt) {
      const int colw = col0 + nt * 16 + lr;
      const f32x4* pb = (const f32x4*)(W1 + (size_t)colw * HH + k);
      f16x8 bf = cvt8(pb[0], pb[1]);
      acch[nt] = __builtin_amdgcn_mfma_f32_16x16x32_f16(ahi, bf, acch[nt], 0, 0, 0);
      accl[nt] = __builtin_amdgcn_mfma_f32_16x16x32_f16(alo, bf, accl[nt], 0, 0, 0);
    }
  }
#pragma unroll
  for (int nt = 0; nt < 4; ++nt)
#pragma unroll
    for (int j = 0; j < 4; ++j)
      red[w][lk * 4 + j][nt * 16 + lr] = acch[nt][j] + accl[nt][j] * (1.0f / 4096.0f);
  __syncthreads();

  const int r = tid >> 4, cc0 = (tid & 15) * 4;
  const int grow = row0 + r;
#pragma unroll
  for (int i = 0; i < 4; ++i) {
    const int col = col0 + cc0 + i;
    float s = red[0][r][cc0 + i] + red[1][r][cc0 + i] +
              red[2][r][cc0 + i] + red[3][r][cc0 + i] + b1[col];
    z[(size_t)grow * HH + col] = fmaxf(s, 0.0f);
  }
}

// ---------------- K4: y = z @ W2^T + b2. One block per batch row, fp32 wave reduce.
__global__ __launch_bounds__(256) void k_mlp2(const float* __restrict__ z,
                                              const float* __restrict__ W2,
                                              const float* __restrict__ b2,
                                              float* __restrict__ out) {
  __shared__ float redy[4][CC];
  const int b = blockIdx.x;
  const int tid = threadIdx.x;
  const int w = tid >> 6, lane = tid & 63;
  const int k = w * 256 + lane * 4;

  const f32x4 z4 = *(const f32x4*)(z + (size_t)b * HH + k);
  float part[CC];
#pragma unroll
  for (int c = 0; c < CC; ++c) {
    const f32x4 w4 = *(const f32x4*)(W2 + (size_t)c * HH + k);
    part[c] = z4.x * w4.x + z4.y * w4.y + z4.z * w4.z + z4.w * w4.w;
  }
#pragma unroll
  for (int c = 0; c < CC; ++c) {
    float v = part[c];
    for (int off = 32; off; off >>= 1) v += __shfl_down(v, off, 64);
    if (lane == 0) redy[w][c] = v;
  }
  __syncthreads();
  if (tid < CC)
    out[b * CC + tid] = redy[0][tid] + redy[1][tid] + redy[2][tid] + redy[3][tid] + b2[tid];
}

extern "C" void kernel_launch(void* const* d_in, const int* in_sizes, int n_in,
                              void* d_out, int out_size, void* d_ws, size_t ws_size,
                              hipStream_t stream) {
  const int*   x_in  = (const int*)d_in[0];
  const int*   x_len = (const int*)d_in[1];
  const float* emb   = (const float*)d_in[2];
  const float* W_ih  = (const float*)d_in[3];
  const float* b_ih  = (const float*)d_in[4];
  const float* W_hh  = (const float*)d_in[5];
  const float* b_hh  = (const float*)d_in[6];
  const float* W1    = (const float*)d_in[7];
  const float* b1    = (const float*)d_in[8];
  const float* W2    = (const float*)d_in[9];
  const float* b2    = (const float*)d_in[10];

  char* ws = (char*)d_ws;
  _Float16* hbuf = (_Float16*)(ws + HBUF_OFF);
  int* flags     = (int*)(ws + FLAGS_OFF);
  float* ep      = (float*)(ws + EP_OFF);
  float* lastb   = (float*)(ws + LAST_OFF);
  float* z       = (float*)(ws + Z_OFF);

  // h0 = 0 (both planes of buf0) and step-arrival flags = 0
  (void)hipMemsetAsync(hbuf, 0, 0x100000, stream);
  (void)hipMemsetAsync(flags, 0, 16 * SS * 4, stream);

  hipLaunchKernelGGL(k_embproj, dim3(128), dim3(256), 0, stream, emb, W_ih, b_ih, b_hh, ep);
  hipLaunchKernelGGL(k_rnn,    dim3(256), dim3(256), 0, stream, W_hh, x_in, x_len, ep, hbuf, flags, lastb);
  hipLaunchKernelGGL(k_mlp1,   dim3(256), dim3(256), 0, stream, lastb, W1, b1, z);
  hipLaunchKernelGGL(k_mlp2,   dim3(256), dim3(256), 0, stream, z, W2, b2, (float*)d_out);
}